// Round 7
// baseline (66.108 us; speedup 1.0000x reference)
//
#include <hip/hip_runtime.h>

typedef float f32x4 __attribute__((ext_vector_type(4)));
typedef __bf16 bf16x8 __attribute__((ext_vector_type(8)));
typedef int i32x4 __attribute__((ext_vector_type(4)));
typedef unsigned short u16;
typedef unsigned int u32;

#define ALPHA 0.2f
#define LOG2E 1.4426950408889634f

__device__ __forceinline__ u16 f2bf(float x) {
    u32 u = __float_as_uint(x);
    u += 0x7FFFu + ((u >> 16) & 1u);   // RNE; inputs finite
    return (u16)(u >> 16);
}

// ---------------------------------------------------------------------------
// K1: Wh = h @ W^T (fp32 register-tiled), fused e_i/e_j, bf16 Wh^T store.
// 256 blocks x 256 thr. (verified rounds 1-6)
// ---------------------------------------------------------------------------
__global__ __launch_bounds__(256) void k_wh(
    const float* __restrict__ hsrc, const float* __restrict__ Wsrc,
    const float* __restrict__ asrc,
    u16* __restrict__ WhbT,          // [8][64][2048] bf16 (f-major, m contiguous)
    float* __restrict__ ei, float* __restrict__ ej)
{
    __shared__ float Wl[64][68];
    __shared__ float hl[64][68];
    __shared__ __align__(16) u16 tl[4096];

    const int tid = threadIdx.x;
    const int tx = tid & 15, ty = tid >> 4;
    const int R0 = blockIdx.x * 64;

    float acc[4][4] = {};

    for (int kc = 0; kc < 4; ++kc) {
        const int k0 = kc * 64;
        __syncthreads();
        #pragma unroll
        for (int p = 0; p < 4; ++p) {
            int idx = p * 1024 + tid * 4;
            int row = idx >> 6, k = idx & 63;
            float4 wv4 = *reinterpret_cast<const float4*>(&Wsrc[row * 256 + k0 + k]);
            Wl[k + 0][row] = wv4.x; Wl[k + 1][row] = wv4.y;
            Wl[k + 2][row] = wv4.z; Wl[k + 3][row] = wv4.w;
            float4 hv4 = *reinterpret_cast<const float4*>(&hsrc[(size_t)(R0 + row) * 256 + k0 + k]);
            hl[k + 0][row] = hv4.x; hl[k + 1][row] = hv4.y;
            hl[k + 2][row] = hv4.z; hl[k + 3][row] = hv4.w;
        }
        __syncthreads();
        #pragma unroll 4
        for (int k = 0; k < 64; ++k) {
            float4 hv = *reinterpret_cast<const float4*>(&hl[k][4 * ty]);
            float4 wv = *reinterpret_cast<const float4*>(&Wl[k][4 * tx]);
            float hr[4] = {hv.x, hv.y, hv.z, hv.w};
            float wc[4] = {wv.x, wv.y, wv.z, wv.w};
            #pragma unroll
            for (int i = 0; i < 4; ++i)
                #pragma unroll
                for (int j = 0; j < 4; ++j)
                    acc[i][j] = fmaf(hr[i], wc[j], acc[i][j]);
        }
    }

    float4 av_i = *reinterpret_cast<const float4*>(&asrc[4 * tx]);
    float4 av_j = *reinterpret_cast<const float4*>(&asrc[64 + 4 * tx]);
    #pragma unroll
    for (int i = 0; i < 4; ++i) {
        float pi = acc[i][0]*av_i.x + acc[i][1]*av_i.y + acc[i][2]*av_i.z + acc[i][3]*av_i.w;
        float pj = acc[i][0]*av_j.x + acc[i][1]*av_j.y + acc[i][2]*av_j.z + acc[i][3]*av_j.w;
        #pragma unroll
        for (int off = 1; off < 16; off <<= 1) {
            pi += __shfl_xor(pi, off, 64);
            pj += __shfl_xor(pj, off, 64);
        }
        if (tx == 0) {
            ei[R0 + 4 * ty + i] = pi;
            ej[R0 + 4 * ty + i] = pj;
        }
    }

    #pragma unroll
    for (int i = 0; i < 4; ++i)
        #pragma unroll
        for (int j = 0; j < 4; ++j) {
            int row = 4 * tx + j;    // o
            int col = 4 * ty + i;    // r
            tl[(row * 64 + col) ^ ((row & 7) << 3)] = f2bf(acc[i][j]);
        }
    __syncthreads();
    {
        const int b = blockIdx.x >> 5;
        const int nloc = (blockIdx.x & 31) * 64;
        const int o = tid >> 2, rg = tid & 3;
        #pragma unroll
        for (int c = 0; c < 2; ++c) {
            int u = (o * 64 + rg * 16 + 8 * c) ^ ((o & 7) << 3);
            int4 v = *reinterpret_cast<const int4*>(&tl[u]);
            *reinterpret_cast<int4*>(&WhbT[(size_t)(b * 64 + o) * 2048 + nloc + rg * 16 + 8 * c]) = v;
        }
    }
}

// ---------------------------------------------------------------------------
// K2: attention partials. 512 blocks (8b x 32nt x 2mt) x 256 thr; 2 blocks/CU.
// adj streamed ONCE (only loop VMEM, 8-deep register prefetch that SURVIVES
// panel boundaries: double-buffered Wh panel + raw s_barrier with only
// lgkmcnt(0) -- no vmcnt drain). ej (scaled by log2e) staged once.
// p = adj ? exp2(lrelu2 - M2) : 0; 5th MFMA vs ones accumulates denominator.
// ---------------------------------------------------------------------------
__global__ __launch_bounds__(256) void k_attn(
    const int* __restrict__ adj, const u16* __restrict__ WhbT,
    const float* __restrict__ ei_g, const float* __restrict__ ej_g,
    float* __restrict__ nump, float* __restrict__ denp)
{
    __shared__ __align__(16) u16 whl[2 * 64 * 264];   // 2 x 33 KB, row stride 528 B
    __shared__ __align__(16) float ejl[1024];

    const int tid  = threadIdx.x;
    const int lane = tid & 63;
    const int w    = tid >> 6;
    // XCD-contiguous remap: each XCD owns one batch.
    const int lb = (blockIdx.x & 7) * 64 + (blockIdx.x >> 3);
    const int mt = lb & 1;
    const int nt = (lb >> 1) & 31;
    const int b  = lb >> 6;
    const int r  = lane & 15;
    const int ks = lane >> 4;
    const int m0 = mt * 1024;

    // ---- stage ej * log2e (block m-range, 4 KB) ----
    {
        float4 v = *reinterpret_cast<const float4*>(&ej_g[b * 2048 + m0 + tid * 4]);
        v.x *= LOG2E; v.y *= LOG2E; v.z *= LOG2E; v.w *= LOG2E;
        *reinterpret_cast<float4*>(&ejl[tid * 4]) = v;
    }

    // ---- panel-0 global loads (32 KB; thread: f=tid>>2, 8 x int4) ----
    const u16* whb = WhbT + (size_t)b * 131072;
    const int sf = tid >> 2;
    const int su = (tid & 3) * 8;
    int4 pv0, pv1, pv2, pv3, pv4, pv5, pv6, pv7;
#define PLOAD(p) { const u16* pp = whb + sf * 2048 + m0 + (p) * 256 + su * 8; \
    pv0 = *reinterpret_cast<const int4*>(pp);      pv1 = *reinterpret_cast<const int4*>(pp + 8); \
    pv2 = *reinterpret_cast<const int4*>(pp + 16); pv3 = *reinterpret_cast<const int4*>(pp + 24); \
    pv4 = *reinterpret_cast<const int4*>(pp + 32); pv5 = *reinterpret_cast<const int4*>(pp + 40); \
    pv6 = *reinterpret_cast<const int4*>(pp + 48); pv7 = *reinterpret_cast<const int4*>(pp + 56); }
#define PWRITE(d) { char* wp = reinterpret_cast<char*>(whl) + (d) * 33792 + sf * 528 + su * 16; \
    *reinterpret_cast<int4*>(wp)       = pv0; *reinterpret_cast<int4*>(wp + 16)  = pv1; \
    *reinterpret_cast<int4*>(wp + 32)  = pv2; *reinterpret_cast<int4*>(wp + 48)  = pv3; \
    *reinterpret_cast<int4*>(wp + 64)  = pv4; *reinterpret_cast<int4*>(wp + 80)  = pv5; \
    *reinterpret_cast<int4*>(wp + 96)  = pv6; *reinterpret_cast<int4*>(wp + 112) = pv7; }
    PLOAD(0);

    const int* adjp = adj + (size_t)(b * 2048 + nt * 64 + w * 16 + r) * 2048 + m0 + ks * 8;

    // ---- adj rolling prefetch, 8 pairs deep (aligned with 8-step panels) ----
    i32x4 Aa0, Aa1, Ba0, Ba1, Ca0, Ca1, Da0, Da1;
    i32x4 Ea0, Ea1, Fa0, Fa1, Ga0, Ga1, Ha0, Ha1;
#define LADJ(gt, x0, x1) if ((gt) < 32) { \
    x0 = __builtin_nontemporal_load(reinterpret_cast<const i32x4*>(adjp + (gt) * 32)); \
    x1 = __builtin_nontemporal_load(reinterpret_cast<const i32x4*>(adjp + (gt) * 32 + 4)); }
    LADJ(0, Aa0, Aa1); LADJ(1, Ba0, Ba1); LADJ(2, Ca0, Ca1); LADJ(3, Da0, Da1);
    LADJ(4, Ea0, Ea1); LADJ(5, Fa0, Fa1); LADJ(6, Ga0, Ga1); LADJ(7, Ha0, Ha1);

    // ---- Mj = max_m e_j[b,m] (L2-resident) ----
    float mj = -1e30f;
    #pragma unroll
    for (int i = 0; i < 8; ++i) {
        float4 v = *reinterpret_cast<const float4*>(&ej_g[b * 2048 + (i * 64 + lane) * 4]);
        mj = fmaxf(mj, fmaxf(fmaxf(v.x, v.y), fmaxf(v.z, v.w)));
    }
    #pragma unroll
    for (int off = 1; off < 64; off <<= 1) mj = fmaxf(mj, __shfl_xor(mj, off, 64));

    const float eiv2 = ei_g[b * 2048 + nt * 64 + w * 16 + r] * LOG2E;
    const float xM2  = eiv2 + mj * LOG2E;
    const float M2   = fmaxf(xM2, ALPHA * xM2);   // log2-domain upper bound

    bf16x8 bones;
    {
        const float o = (r == 0) ? 1.0f : 0.0f;
        #pragma unroll
        for (int j = 0; j < 8; ++j) bones[j] = (__bf16)o;
    }

    PWRITE(0);
    __syncthreads();   // one-time full sync (panel 0 + ejl visible)

    f32x4 acc0 = {}, acc1 = {}, acc2 = {}, acc3 = {}, acc4 = {};

    const char* wl0 = reinterpret_cast<const char*>(whl) + r * 528 + ks * 16;
    const char* wl1 = wl0 + 33792;
    const float* eb = ejl + ks * 8;

// raw panel barrier: LDS-write visibility WITHOUT draining vmcnt (adj stays in flight)
#define PBAR() { asm volatile("s_waitcnt lgkmcnt(0)" ::: "memory"); \
    __builtin_amdgcn_sched_barrier(0); \
    __builtin_amdgcn_s_barrier(); \
    __builtin_amdgcn_sched_barrier(0); }

#define PVAL(mk, ev, dst) { \
    float x_ = eiv2 + (ev); \
    float lr_ = fmaxf(x_, ALPHA * x_); \
    float p_ = exp2f(lr_ - M2); \
    dst = (__bf16)(((mk) != 0) ? p_ : 0.0f); }

#define STEP(gt, x0, x1, wl) { \
    const int tl_ = (gt) & 7; \
    float4 e0 = *reinterpret_cast<const float4*>(eb + (gt) * 32); \
    float4 e1 = *reinterpret_cast<const float4*>(eb + (gt) * 32 + 4); \
    bf16x8 af; \
    PVAL(x0[0], e0.x, af[0]); PVAL(x0[1], e0.y, af[1]); \
    PVAL(x0[2], e0.z, af[2]); PVAL(x0[3], e0.w, af[3]); \
    PVAL(x1[0], e1.x, af[4]); PVAL(x1[1], e1.y, af[5]); \
    PVAL(x1[2], e1.z, af[6]); PVAL(x1[3], e1.w, af[7]); \
    bf16x8 w0 = *reinterpret_cast<const bf16x8*>(wl + tl_ * 64); \
    bf16x8 w1 = *reinterpret_cast<const bf16x8*>(wl + tl_ * 64 + 16 * 528); \
    bf16x8 w2 = *reinterpret_cast<const bf16x8*>(wl + tl_ * 64 + 32 * 528); \
    bf16x8 w3 = *reinterpret_cast<const bf16x8*>(wl + tl_ * 64 + 48 * 528); \
    acc0 = __builtin_amdgcn_mfma_f32_16x16x32_bf16(af, w0, acc0, 0, 0, 0); \
    acc1 = __builtin_amdgcn_mfma_f32_16x16x32_bf16(af, w1, acc1, 0, 0, 0); \
    acc2 = __builtin_amdgcn_mfma_f32_16x16x32_bf16(af, w2, acc2, 0, 0, 0); \
    acc3 = __builtin_amdgcn_mfma_f32_16x16x32_bf16(af, w3, acc3, 0, 0, 0); \
    acc4 = __builtin_amdgcn_mfma_f32_16x16x32_bf16(af, bones, acc4, 0, 0, 0); }

#define PANEL8(base, wl) \
    STEP((base)+0, Aa0, Aa1, wl); LADJ((base)+8,  Aa0, Aa1); \
    STEP((base)+1, Ba0, Ba1, wl); LADJ((base)+9,  Ba0, Ba1); \
    STEP((base)+2, Ca0, Ca1, wl); LADJ((base)+10, Ca0, Ca1); \
    STEP((base)+3, Da0, Da1, wl); LADJ((base)+11, Da0, Da1); \
    STEP((base)+4, Ea0, Ea1, wl); LADJ((base)+12, Ea0, Ea1); \
    STEP((base)+5, Fa0, Fa1, wl); LADJ((base)+13, Fa0, Fa1); \
    STEP((base)+6, Ga0, Ga1, wl); LADJ((base)+14, Ga0, Ga1); \
    STEP((base)+7, Ha0, Ha1, wl); LADJ((base)+15, Ha0, Ha1);

    // panel 0 (reads buf0); prefetch panel 1 into regs, write buf1 at end
    PLOAD(1);
    PANEL8(0, wl0);
    PWRITE(1); PBAR();

    // panel 1 (buf1)
    PLOAD(2);
    PANEL8(8, wl1);
    PWRITE(0); PBAR();

    // panel 2 (buf0)
    PLOAD(3);
    PANEL8(16, wl0);
    PWRITE(1); PBAR();

    // panel 3 (buf1)
    PANEL8(24, wl1);

#undef PANEL8
#undef STEP
#undef PVAL
#undef PBAR
#undef LADJ
#undef PWRITE
#undef PLOAD

    // ---- epilogue: partial num/den stores (coalesced, no atomics) ----
    const size_t nb0 = (size_t)mt * 16384 + b * 2048 + nt * 64 + w * 16;
    #pragma unroll
    for (int q = 0; q < 4; ++q) {
        const int rr = ks * 4 + q;
        float* np = nump + (nb0 + rr) * 64 + r;
        np[0]  = acc0[q];
        np[16] = acc1[q];
        np[32] = acc2[q];
        np[48] = acc3[q];
        if (r == 0) denp[nb0 + rr] = acc4[q];
    }
}

// ---------------------------------------------------------------------------
// K3: combine the 2 m-half partials and normalize. 1024 blocks x 256 thr.
// ---------------------------------------------------------------------------
__global__ __launch_bounds__(256) void k_norm(
    const float* __restrict__ nump, const float* __restrict__ denp,
    float* __restrict__ out)
{
    const int tid = threadIdx.x;
    const int f4 = tid & 15;
    const size_t N = (size_t)blockIdx.x * 16 + (tid >> 4);
    const float d = denp[N] + denp[16384 + N];
    const float inv = (d > 0.0f) ? 1.0f / d : 0.0f;   // all-masked row -> 0
    float4 a = *reinterpret_cast<const float4*>(&nump[N * 64 + f4 * 4]);
    float4 c = *reinterpret_cast<const float4*>(&nump[(16384 + N) * 64 + f4 * 4]);
    float4 o;
    o.x = (a.x + c.x) * inv; o.y = (a.y + c.y) * inv;
    o.z = (a.z + c.z) * inv; o.w = (a.w + c.w) * inv;
    *reinterpret_cast<float4*>(&out[N * 64 + f4 * 4]) = o;
}

// ---------------------------------------------------------------------------
extern "C" void kernel_launch(void* const* d_in, const int* in_sizes, int n_in,
                              void* d_out, int out_size, void* d_ws, size_t ws_size,
                              hipStream_t stream)
{
    const float* h   = (const float*)d_in[0];   // [8,2048,256]
    const int*   adj = (const int*)d_in[1];     // [8,2048,2048]
    const float* W   = (const float*)d_in[2];   // [64,256]
    const float* a   = (const float*)d_in[3];   // [1,128]
    float* out = (float*)d_out;                  // [8,2048,64]

    u16*   WhbT = (u16*)d_ws;                                    // 2 MB
    float* ei   = (float*)((char*)d_ws + 2 * 1024 * 1024);       // 64 KB
    float* ej   = ei + 16384;                                    // 64 KB
    float* nump = (float*)((char*)d_ws + 4 * 1024 * 1024);       // 8 MB [2][16384][64]
    float* denp = (float*)((char*)d_ws + 12 * 1024 * 1024);      // 128 KB [2][16384]

    k_wh  <<<dim3(256),  dim3(256), 0, stream>>>(h, W, a, WhbT, ei, ej);
    k_attn<<<dim3(512),  dim3(256), 0, stream>>>(adj, WhbT, ei, ej, nump, denp);
    k_norm<<<dim3(1024), dim3(256), 0, stream>>>(nump, denp, out);
}